// Round 5
// baseline (2641.456 us; speedup 1.0000x reference)
//
#include <hip/hip_runtime.h>
#include <hip/hip_bf16.h>

#define D_DIM 512
#define S_LEN 12
#define H_NUM 8
#define G_B 4
#define ROWS 48           // G_B * S_LEN = 3 exact M-tiles
#define THREADS 512       // 8 waves, wave w <-> head w
#define WMAT 262144       // 512*512

// LDS byte offsets
#define QB_OFF  0         // 8 waves x [48][64] bf16 = 49152 B   (aliased by A-stage later)
#define KB_OFF  49152
#define VB_OFF  98304
#define PB_OFF  147456    // 8 x [12][20] f32 = 7680 B
#define RED_OFF 155136    // [48][17] f32 = 3264 B
#define MU_OFF  158400    // [48][2] f32 = 384 B
#define SMEM_BYTES 158784 // <= 160 KiB, 1 block/CU

typedef __attribute__((ext_vector_type(8))) short bf16x8;
typedef __attribute__((ext_vector_type(4))) float f32x4;

__device__ __forceinline__ unsigned short f2bf(float f) {
    union { float f; unsigned u; } c; c.f = f;
    unsigned r = c.u + 0x7fffu + ((c.u >> 16) & 1u);
    return (unsigned short)(r >> 16);
}
__device__ __forceinline__ float bf2f(unsigned short u) {
    union { unsigned u; float f; } c; c.u = ((unsigned)u) << 16;
    return c.f;
}
// 16B-granule XOR swizzles (chunk ^= row&7)
__device__ __forceinline__ int xswc(int row, int col) {  // 512-col tiles
    return row * 512 + (((col >> 3) ^ (row & 7)) << 3) + (col & 7);
}
__device__ __forceinline__ int qsw(int row, int col) {   // 64-col tiles
    return row * 64 + (((col >> 3) ^ (row & 7)) << 3) + (col & 7);
}

__global__ void prep_weights(const float* __restrict__ Wq, const float* __restrict__ Wk,
                             const float* __restrict__ Wv, const float* __restrict__ Wo,
                             unsigned short* __restrict__ wt) {
    int idx = blockIdx.x * 256 + threadIdx.x;   // 0 .. 4*WMAT-1
    int mat = idx >> 18;
    int rem = idx & (WMAT - 1);
    int e = rem >> 9, d = rem & 511;
    const float* W = (mat == 0) ? Wq : (mat == 1) ? Wk : (mat == 2) ? Wv : Wo;
    wt[idx] = f2bf(W[d * D_DIM + e]);           // wt[mat][e][d] = W[d][e]
}

__global__ __launch_bounds__(THREADS, 2) void fused_attn(
    const float* __restrict__ x, const unsigned short* __restrict__ wt,
    const float* __restrict__ bq, const float* __restrict__ bk, const float* __restrict__ bv,
    const float* __restrict__ adj, const float* __restrict__ bo,
    const float* __restrict__ gamma, const float* __restrict__ beta,
    float* __restrict__ out)
{
    extern __shared__ char smem[];
    unsigned short* Qb  = (unsigned short*)(smem + QB_OFF);
    unsigned short* Kb  = (unsigned short*)(smem + KB_OFF);
    unsigned short* Vb  = (unsigned short*)(smem + VB_OFF);
    unsigned short* Ast = (unsigned short*)(smem + QB_OFF);  // [48][512] bf16, aliases dead Q-bufs
    float* red   = (float*)(smem + RED_OFF);   // [48][17]
    float* musig = (float*)(smem + MU_OFF);    // [48][2]

    const int tid  = threadIdx.x;
    const int lane = tid & 63;
    const int w    = tid >> 6;          // wave = head, 0..7
    const int lr   = lane & 15;
    const int lg   = lane >> 4;
    const int lr12 = (lr < 12) ? lr : 11;
    const size_t row0 = (size_t)blockIdx.x * ROWS;

    float* Pw = (float*)(smem + PB_OFF) + w * 240;   // wave-private [12][20]
    unsigned short* Qw = Qb + w * 3072;              // wave-private [48][64]
    unsigned short* Kw = Kb + w * 3072;
    unsigned short* Vw = Vb + w * 3072;

    // ---------------- QKV GEMM for head w: M=48, N=64 x 3 mats, K=512 ----------------
    // A-fragments straight from global x (fp32 -> bf16 pack); B from L2-resident wt.
    f32x4 acc[3][3][4];                 // [mat][mt][nt]
    #pragma unroll
    for (int a = 0; a < 3; ++a)
        #pragma unroll
        for (int b2 = 0; b2 < 3; ++b2)
            #pragma unroll
            for (int c = 0; c < 4; ++c) acc[a][b2][c] = (f32x4){0.f, 0.f, 0.f, 0.f};

    #pragma unroll 2
    for (int ks = 0; ks < 16; ++ks) {
        bf16x8 af[3];
        #pragma unroll
        for (int mt = 0; mt < 3; ++mt) {
            const float* xp = x + (row0 + mt * 16 + lr) * (size_t)D_DIM + ks * 32 + lg * 8;
            float4 a0 = *(const float4*)xp;
            float4 a1 = *(const float4*)(xp + 4);
            bf16x8 t;
            t[0] = (short)f2bf(a0.x); t[1] = (short)f2bf(a0.y);
            t[2] = (short)f2bf(a0.z); t[3] = (short)f2bf(a0.w);
            t[4] = (short)f2bf(a1.x); t[5] = (short)f2bf(a1.y);
            t[6] = (short)f2bf(a1.z); t[7] = (short)f2bf(a1.w);
            af[mt] = t;
        }
        #pragma unroll
        for (int mat = 0; mat < 3; ++mat)
            #pragma unroll
            for (int nt = 0; nt < 4; ++nt) {
                bf16x8 bfv = *(const bf16x8*)(wt + (size_t)mat * WMAT +
                                              (w * 64 + nt * 16 + lr) * D_DIM + ks * 32 + lg * 8);
                #pragma unroll
                for (int mt = 0; mt < 3; ++mt)
                    acc[mat][mt][nt] = __builtin_amdgcn_mfma_f32_16x16x32_bf16(af[mt], bfv, acc[mat][mt][nt], 0, 0, 0);
            }
    }
    // store Q/K/V (+bias) to wave-private LDS (no barrier needed: wave-private)
    {
        const float* bptr[3] = {bq, bk, bv};
        #pragma unroll
        for (int mat = 0; mat < 3; ++mat) {
            unsigned short* T = (mat == 0) ? Qw : (mat == 1) ? Kw : Vw;
            #pragma unroll
            for (int nt = 0; nt < 4; ++nt) {
                float bias = bptr[mat][w * 64 + nt * 16 + lr];
                #pragma unroll
                for (int mt = 0; mt < 3; ++mt)
                    #pragma unroll
                    for (int j = 0; j < 4; ++j)
                        T[qsw(mt * 16 + lg * 4 + j, nt * 16 + lr)] = f2bf(acc[mat][mt][nt][j] + bias);
            }
        }
    }

    // ---------------- attention: 4 batch items, fully wave-private ----------------
    float oA[48];
    #pragma unroll
    for (int bb = 0; bb < 4; ++bb) {
        const int rb = bb * S_LEN;
        f32x4 sacc = (f32x4){0.f, 0.f, 0.f, 0.f};
        #pragma unroll
        for (int k2 = 0; k2 < 2; ++k2) {
            bf16x8 ak = *(const bf16x8*)(Kw + qsw(rb + lr12, k2 * 32 + lg * 8));
            bf16x8 aq = *(const bf16x8*)(Qw + qsw(rb + lr12, k2 * 32 + lg * 8));
            sacc = __builtin_amdgcn_mfma_f32_16x16x32_bf16(ak, aq, sacc, 0, 0, 0);
        }
        float ab4[4] = {0.f, 0.f, 0.f, 0.f};
        if (lg < 3 && lr < 12) {
            float4 t4 = *(const float4*)(adj + (w * S_LEN + lr) * S_LEN + lg * 4);
            ab4[0] = t4.x; ab4[1] = t4.y; ab4[2] = t4.z; ab4[3] = t4.w;
        }
        float sc[4], e4[4];
        float m = -1e30f;
        #pragma unroll
        for (int j = 0; j < 4; ++j) {
            int t = lg * 4 + j;
            sc[j] = (t < 12) ? (sacc[j] * 0.125f + ab4[j]) : -1e30f;
            m = fmaxf(m, sc[j]);
        }
        m = fmaxf(m, __shfl_xor(m, 16));
        m = fmaxf(m, __shfl_xor(m, 32));
        float ssum = 0.f;
        #pragma unroll
        for (int j = 0; j < 4; ++j) { e4[j] = __expf(sc[j] - m); ssum += e4[j]; }
        ssum += __shfl_xor(ssum, 16);
        ssum += __shfl_xor(ssum, 32);
        float inv = 1.f / ssum;
        if (lr < 12 && lg < 3) {
            f32x4 pvec = (f32x4){e4[0] * inv, e4[1] * inv, e4[2] * inv, e4[3] * inv};
            *(f32x4*)(Pw + lr * 20 + lg * 4) = pvec;
        }
        // same-wave LDS write->read: compiler lgkmcnt ordering is sufficient
        {
            float vv[12];
            #pragma unroll
            for (int t = 0; t < 12; ++t) vv[t] = bf2f(Vw[qsw(rb + t, lane)]);
            #pragma unroll
            for (int ss = 0; ss < 12; ++ss) {
                f32x4 pa = *(const f32x4*)(Pw + ss * 20);
                f32x4 pb = *(const f32x4*)(Pw + ss * 20 + 4);
                f32x4 pc = *(const f32x4*)(Pw + ss * 20 + 8);
                float o = 0.f;
                #pragma unroll
                for (int t = 0; t < 4; ++t) o += pa[t] * vv[t];
                #pragma unroll
                for (int t = 0; t < 4; ++t) o += pb[t] * vv[4 + t];
                #pragma unroll
                for (int t = 0; t < 4; ++t) o += pc[t] * vv[8 + t];
                oA[rb + ss] = o;
            }
        }
    }

    __syncthreads();   // all waves done reading Q/K/V bufs -> safe to alias Qb with Ast
    #pragma unroll
    for (int r = 0; r < ROWS; ++r)
        Ast[xswc(r, w * 64 + lane)] = f2bf(oA[r]);
    __syncthreads();   // A-stage complete

    // ---------------- out-projection: M=48, N=64 (wave's cols), K=512 ----------------
    f32x4 Y[3][4];
    #pragma unroll
    for (int mt = 0; mt < 3; ++mt)
        #pragma unroll
        for (int nt = 0; nt < 4; ++nt) Y[mt][nt] = (f32x4){0.f, 0.f, 0.f, 0.f};

    #pragma unroll 2
    for (int ks = 0; ks < 16; ++ks) {
        bf16x8 afr[3];
        #pragma unroll
        for (int mt = 0; mt < 3; ++mt)
            afr[mt] = *(const bf16x8*)(Ast + xswc(mt * 16 + lr, ks * 32 + lg * 8));
        #pragma unroll
        for (int nt = 0; nt < 4; ++nt) {
            bf16x8 bfr = *(const bf16x8*)(wt + (size_t)3 * WMAT +
                                          (w * 64 + nt * 16 + lr) * D_DIM + ks * 32 + lg * 8);
            #pragma unroll
            for (int mt = 0; mt < 3; ++mt)
                Y[mt][nt] = __builtin_amdgcn_mfma_f32_16x16x32_bf16(afr[mt], bfr, Y[mt][nt], 0, 0, 0);
        }
    }

    // ---------------- epilogue: +bo, +x (fp32), LayerNorm, store ----------------
    float bo4[4], gm4[4], bt4[4];
    int cols[4];
    #pragma unroll
    for (int nt = 0; nt < 4; ++nt) {
        cols[nt] = w * 64 + nt * 16 + lr;
        bo4[nt] = bo[cols[nt]]; gm4[nt] = gamma[cols[nt]]; bt4[nt] = beta[cols[nt]];
    }
    #pragma unroll
    for (int mt = 0; mt < 3; ++mt)
        #pragma unroll
        for (int j = 0; j < 4; ++j) {
            int rowl = mt * 16 + lg * 4 + j;
            const float* xrow = x + (row0 + rowl) * (size_t)D_DIM;
            float ps = 0.f, pq = 0.f;
            #pragma unroll
            for (int nt = 0; nt < 4; ++nt) {
                float y = Y[mt][nt][j] + bo4[nt] + xrow[cols[nt]];
                Y[mt][nt][j] = y;
                ps += y; pq += y * y;
            }
            ps += __shfl_xor(ps, 1); pq += __shfl_xor(pq, 1);
            ps += __shfl_xor(ps, 2); pq += __shfl_xor(pq, 2);
            ps += __shfl_xor(ps, 4); pq += __shfl_xor(pq, 4);
            ps += __shfl_xor(ps, 8); pq += __shfl_xor(pq, 8);
            if (lr == 0) { red[rowl * 17 + w * 2] = ps; red[rowl * 17 + w * 2 + 1] = pq; }
        }
    __syncthreads();
    if (tid < ROWS) {
        float s = 0.f, q = 0.f;
        #pragma unroll
        for (int w8 = 0; w8 < 8; ++w8) { s += red[tid * 17 + w8 * 2]; q += red[tid * 17 + w8 * 2 + 1]; }
        float mu = s * (1.f / 512.f);
        float var = q * (1.f / 512.f) - mu * mu;
        musig[tid * 2] = mu;
        musig[tid * 2 + 1] = rsqrtf(var + 1e-5f);
    }
    __syncthreads();
    #pragma unroll
    for (int mt = 0; mt < 3; ++mt)
        #pragma unroll
        for (int j = 0; j < 4; ++j) {
            int rowl = mt * 16 + lg * 4 + j;
            float mu = musig[rowl * 2], rs = musig[rowl * 2 + 1];
            float* orow = out + (row0 + rowl) * (size_t)D_DIM;
            #pragma unroll
            for (int nt = 0; nt < 4; ++nt)
                orow[cols[nt]] = (Y[mt][nt][j] - mu) * rs * gm4[nt] + bt4[nt];
        }
}

extern "C" void kernel_launch(void* const* d_in, const int* in_sizes, int n_in,
                              void* d_out, int out_size, void* d_ws, size_t ws_size,
                              hipStream_t stream) {
    (void)in_sizes; (void)n_in; (void)out_size; (void)ws_size;
    const float* x     = (const float*)d_in[0];
    const float* Wq    = (const float*)d_in[1];
    const float* bq    = (const float*)d_in[2];
    const float* Wk    = (const float*)d_in[3];
    const float* bk    = (const float*)d_in[4];
    const float* Wv    = (const float*)d_in[5];
    const float* bv    = (const float*)d_in[6];
    const float* adj   = (const float*)d_in[7];
    const float* Wo    = (const float*)d_in[8];
    const float* bo    = (const float*)d_in[9];
    const float* gamma = (const float*)d_in[10];
    const float* beta  = (const float*)d_in[11];
    unsigned short* wt = (unsigned short*)d_ws;      // 4 * 512*512 bf16 = 2 MiB

    prep_weights<<<4096, 256, 0, stream>>>(Wq, Wk, Wv, Wo, wt);
    fused_attn<<<16384 / G_B, THREADS, SMEM_BYTES, stream>>>(
        x, wt, bq, bk, bv, adj, bo, gamma, beta, (float*)d_out);
}

// Round 6
// 2095.522 us; speedup vs baseline: 1.2605x; 1.2605x over previous
//
#include <hip/hip_runtime.h>
#include <hip/hip_bf16.h>

#define D_DIM 512
#define S_LEN 12
#define H_NUM 8
#define G_B 4
#define ROWS 48           // G_B * S_LEN = 3 exact M-tiles
#define THREADS 512       // 8 waves
#define WMAT 262144       // 512*512

// LDS byte offsets (tiles XOR-swizzled, no padding)
#define X_OFF   0         // [48][512] bf16 = 49152
#define Q_OFF   49152     // [48][64] bf16 = 6144
#define K_OFF   55296
#define V_OFF   61440
#define A_OFF   67584
#define P_OFF   73728     // 4 x [12][20] f32 = 3840
#define RED_OFF 77568     // [48][17] f32 = 3264
#define MU_OFF  80832     // [48][2] f32 = 384
#define SMEM_BYTES 81216  // x2 = 162432 <= 163840 -> 2 blocks/CU (16 waves/CU)

typedef __attribute__((ext_vector_type(8))) short bf16x8;
typedef __attribute__((ext_vector_type(4))) float f32x4;

__device__ __forceinline__ unsigned short f2bf(float f) {
    union { float f; unsigned u; } c; c.f = f;
    unsigned r = c.u + 0x7fffu + ((c.u >> 16) & 1u);
    return (unsigned short)(r >> 16);
}
__device__ __forceinline__ float bf2f(unsigned short u) {
    union { unsigned u; float f; } c; c.u = ((unsigned)u) << 16;
    return c.f;
}
// 16B-granule XOR swizzles (chunk ^= row&7)
__device__ __forceinline__ int xswc(int row, int col) {  // 512-col tiles
    return row * 512 + (((col >> 3) ^ (row & 7)) << 3) + (col & 7);
}
__device__ __forceinline__ int qsw(int row, int col) {   // 64-col tiles
    return row * 64 + (((col >> 3) ^ (row & 7)) << 3) + (col & 7);
}

__global__ void prep_weights(const float* __restrict__ Wq, const float* __restrict__ Wk,
                             const float* __restrict__ Wv, const float* __restrict__ Wo,
                             unsigned short* __restrict__ wt) {
    int idx = blockIdx.x * 256 + threadIdx.x;   // 0 .. 4*WMAT-1
    int mat = idx >> 18;
    int rem = idx & (WMAT - 1);
    int e = rem >> 9, d = rem & 511;
    const float* W = (mat == 0) ? Wq : (mat == 1) ? Wk : (mat == 2) ? Wv : Wo;
    wt[idx] = f2bf(W[d * D_DIM + e]);           // wt[mat][e][d] = W[d][e]
}

__global__ __launch_bounds__(THREADS, 4) void fused_attn(
    const float* __restrict__ x, const unsigned short* __restrict__ wt,
    const float* __restrict__ bq, const float* __restrict__ bk, const float* __restrict__ bv,
    const float* __restrict__ adj, const float* __restrict__ bo,
    const float* __restrict__ gamma, const float* __restrict__ beta,
    float* __restrict__ out)
{
    extern __shared__ char smem[];
    unsigned short* Xh = (unsigned short*)(smem + X_OFF);
    unsigned short* Qh = (unsigned short*)(smem + Q_OFF);
    unsigned short* Kh = (unsigned short*)(smem + K_OFF);
    unsigned short* Vh = (unsigned short*)(smem + V_OFF);
    unsigned short* Ah = (unsigned short*)(smem + A_OFF);
    float* Pl    = (float*)(smem + P_OFF);      // [4][12][20]
    float* red   = (float*)(smem + RED_OFF);    // [48][17]
    float* musig = (float*)(smem + MU_OFF);     // [48][2]

    const int tid  = threadIdx.x;
    const int lane = tid & 63;
    const int w    = tid >> 6;          // wave 0..7
    const int lr   = lane & 15;
    const int lg   = lane >> 4;
    const int lr12 = (lr < 12) ? lr : 11;       // true clamp
    const size_t row0 = (size_t)blockIdx.x * ROWS;

    // ---------------- phase 0: stage X -> LDS bf16 (swizzled) ----------------
    #pragma unroll
    for (int it = 0; it < 12; ++it) {
        int idx = it * THREADS + tid;            // 6144 chunks of 4 floats
        int r = idx >> 7, col = (idx & 127) << 2;
        float4 v = *(const float4*)(x + (row0 + r) * (size_t)D_DIM + col);
        ushort4 pk;
        pk.x = f2bf(v.x); pk.y = f2bf(v.y); pk.z = f2bf(v.z); pk.w = f2bf(v.w);
        *(ushort4*)(Xh + xswc(r, col)) = pk;
    }
    __syncthreads();

    // persistent out-proj accumulators: wave w owns cols [w*64, w*64+64)
    f32x4 Y[3][4];
    #pragma unroll
    for (int mt = 0; mt < 3; ++mt)
        #pragma unroll
        for (int nt = 0; nt < 4; ++nt) Y[mt][nt] = (f32x4){0.f, 0.f, 0.f, 0.f};

    // QKV task mapping (12 tasks = 3 mats x 4 col-tiles over 8 waves):
    //  waves 0-3: taskA = (Q, colt=w),  taskB = (V, colt=w)
    //  waves 4-7: taskA = (K, colt=w-4), no taskB
    const bool twoTask = (w < 4);
    const int colt = w & 3;
    const int colh = colt * 16 + lr;             // col within head (0..63)
    const int matA = twoTask ? 0 : 1;
    const int rb = w * S_LEN;                    // attention rows (waves 0-3)

    #pragma unroll 1
    for (int h = 0; h < H_NUM; ++h) {
        // ---------------- QKV projection for head h ----------------
        f32x4 accA[3], accB[3];
        #pragma unroll
        for (int mt = 0; mt < 3; ++mt) {
            accA[mt] = (f32x4){0.f, 0.f, 0.f, 0.f};
            accB[mt] = (f32x4){0.f, 0.f, 0.f, 0.f};
        }
        const unsigned short* bAp = wt + (size_t)matA * WMAT + (h * 64 + colh) * D_DIM;
        const unsigned short* bBp = wt + (size_t)2 * WMAT + (h * 64 + colh) * D_DIM;
        #pragma unroll
        for (int ks = 0; ks < 16; ++ks) {
            bf16x8 af[3];
            #pragma unroll
            for (int mt = 0; mt < 3; ++mt)
                af[mt] = *(const bf16x8*)(Xh + xswc(mt * 16 + lr, ks * 32 + lg * 8));
            bf16x8 b0 = *(const bf16x8*)(bAp + ks * 32 + lg * 8);
            #pragma unroll
            for (int mt = 0; mt < 3; ++mt)
                accA[mt] = __builtin_amdgcn_mfma_f32_16x16x32_bf16(af[mt], b0, accA[mt], 0, 0, 0);
            if (twoTask) {
                bf16x8 b1 = *(const bf16x8*)(bBp + ks * 32 + lg * 8);
                #pragma unroll
                for (int mt = 0; mt < 3; ++mt)
                    accB[mt] = __builtin_amdgcn_mfma_f32_16x16x32_bf16(af[mt], b1, accB[mt], 0, 0, 0);
            }
        }
        {
            const float* bselA = twoTask ? bq : bk;
            unsigned short* TA = twoTask ? Qh : Kh;
            float biasA = bselA[h * 64 + colh];
            #pragma unroll
            for (int mt = 0; mt < 3; ++mt)
                #pragma unroll
                for (int j = 0; j < 4; ++j)
                    TA[qsw(mt * 16 + lg * 4 + j, colh)] = f2bf(accA[mt][j] + biasA);
            if (twoTask) {
                float biasB = bv[h * 64 + colh];
                #pragma unroll
                for (int mt = 0; mt < 3; ++mt)
                    #pragma unroll
                    for (int j = 0; j < 4; ++j)
                        Vh[qsw(mt * 16 + lg * 4 + j, colh)] = f2bf(accB[mt][j] + biasB);
            }
        }
        __syncthreads();   // barrier 1: Q/K/V complete

        // ---------------- attention (waves 0-3, batch item w) ----------------
        if (twoTask) {
            f32x4 sacc = (f32x4){0.f, 0.f, 0.f, 0.f};
            #pragma unroll
            for (int k2 = 0; k2 < 2; ++k2) {
                bf16x8 ak = *(const bf16x8*)(Kh + qsw(rb + lr12, k2 * 32 + lg * 8));
                bf16x8 aq = *(const bf16x8*)(Qh + qsw(rb + lr12, k2 * 32 + lg * 8));
                sacc = __builtin_amdgcn_mfma_f32_16x16x32_bf16(ak, aq, sacc, 0, 0, 0);
            }
            float ab4[4] = {0.f, 0.f, 0.f, 0.f};
            if (lg < 3 && lr < 12) {
                float4 t4 = *(const float4*)(adj + (h * S_LEN + lr) * S_LEN + lg * 4);
                ab4[0] = t4.x; ab4[1] = t4.y; ab4[2] = t4.z; ab4[3] = t4.w;
            }
            float sc[4], e4[4];
            float m = -1e30f;
            #pragma unroll
            for (int j = 0; j < 4; ++j) {
                int t = lg * 4 + j;
                sc[j] = (t < 12) ? (sacc[j] * 0.125f + ab4[j]) : -1e30f;
                m = fmaxf(m, sc[j]);
            }
            m = fmaxf(m, __shfl_xor(m, 16));
            m = fmaxf(m, __shfl_xor(m, 32));
            float ssum = 0.f;
            #pragma unroll
            for (int j = 0; j < 4; ++j) { e4[j] = __expf(sc[j] - m); ssum += e4[j]; }
            ssum += __shfl_xor(ssum, 16);
            ssum += __shfl_xor(ssum, 32);
            float inv = 1.f / ssum;
            float* Pw = Pl + w * 240;
            if (lr < 12 && lg < 3) {
                f32x4 pvec = (f32x4){e4[0] * inv, e4[1] * inv, e4[2] * inv, e4[3] * inv};
                *(f32x4*)(Pw + lr * 20 + lg * 4) = pvec;
            }
            // same-wave P write -> read: no barrier needed (validated R5)
            float vv[12];
            #pragma unroll
            for (int t = 0; t < 12; ++t) vv[t] = bf2f(Vh[qsw(rb + t, lane)]);
            #pragma unroll
            for (int ss = 0; ss < 12; ++ss) {
                f32x4 pa = *(const f32x4*)(Pw + ss * 20);
                f32x4 pb = *(const f32x4*)(Pw + ss * 20 + 4);
                f32x4 pc = *(const f32x4*)(Pw + ss * 20 + 8);
                float o = 0.f;
                #pragma unroll
                for (int t = 0; t < 4; ++t) o += pa[t] * vv[t];
                #pragma unroll
                for (int t = 0; t < 4; ++t) o += pb[t] * vv[4 + t];
                #pragma unroll
                for (int t = 0; t < 4; ++t) o += pc[t] * vv[8 + t];
                Ah[qsw(rb + ss, lane)] = f2bf(o);
            }
        }
        __syncthreads();   // barrier 2: A complete

        // ---------------- out-projection accumulate (K-slice = head h) ----------------
        const unsigned short* obase = wt + (size_t)3 * WMAT + (w * 64 + lr) * D_DIM + h * 64;
        #pragma unroll
        for (int ks = 0; ks < 2; ++ks) {
            bf16x8 afr[3];
            #pragma unroll
            for (int mt = 0; mt < 3; ++mt)
                afr[mt] = *(const bf16x8*)(Ah + qsw(mt * 16 + lr, ks * 32 + lg * 8));
            #pragma unroll
            for (int nt = 0; nt < 4; ++nt) {
                bf16x8 bfr = *(const bf16x8*)(obase + nt * 16 * D_DIM + ks * 32 + lg * 8);
                #pragma unroll
                for (int mt = 0; mt < 3; ++mt)
                    Y[mt][nt] = __builtin_amdgcn_mfma_f32_16x16x32_bf16(afr[mt], bfr, Y[mt][nt], 0, 0, 0);
            }
        }
        // no trailing barrier: next head's A-writes happen after next barrier 1,
        // which orders them after this phase's A-reads.
    }

    // ---------------- epilogue: +bo, +x (fp32), LayerNorm, store ----------------
    float bo4[4], gm4[4], bt4[4];
    int cols[4];
    #pragma unroll
    for (int nt = 0; nt < 4; ++nt) {
        cols[nt] = w * 64 + nt * 16 + lr;
        bo4[nt] = bo[cols[nt]]; gm4[nt] = gamma[cols[nt]]; bt4[nt] = beta[cols[nt]];
    }
    #pragma unroll
    for (int mt = 0; mt < 3; ++mt)
        #pragma unroll
        for (int j = 0; j < 4; ++j) {
            int rowl = mt * 16 + lg * 4 + j;
            const float* xrow = x + (row0 + rowl) * (size_t)D_DIM;
            float ps = 0.f, pq = 0.f;
            #pragma unroll
            for (int nt = 0; nt < 4; ++nt) {
                float y = Y[mt][nt][j] + bo4[nt] + xrow[cols[nt]];
                Y[mt][nt][j] = y;
                ps += y; pq += y * y;
            }
            ps += __shfl_xor(ps, 1); pq += __shfl_xor(pq, 1);
            ps += __shfl_xor(ps, 2); pq += __shfl_xor(pq, 2);
            ps += __shfl_xor(ps, 4); pq += __shfl_xor(pq, 4);
            ps += __shfl_xor(ps, 8); pq += __shfl_xor(pq, 8);
            if (lr == 0) { red[rowl * 17 + w * 2] = ps; red[rowl * 17 + w * 2 + 1] = pq; }
        }
    __syncthreads();
    if (tid < ROWS) {
        float s = 0.f, q = 0.f;
        #pragma unroll
        for (int w8 = 0; w8 < 8; ++w8) { s += red[tid * 17 + w8 * 2]; q += red[tid * 17 + w8 * 2 + 1]; }
        float mu = s * (1.f / 512.f);
        float var = q * (1.f / 512.f) - mu * mu;
        musig[tid * 2] = mu;
        musig[tid * 2 + 1] = rsqrtf(var + 1e-5f);
    }
    __syncthreads();
    #pragma unroll
    for (int mt = 0; mt < 3; ++mt)
        #pragma unroll
        for (int j = 0; j < 4; ++j) {
            int rowl = mt * 16 + lg * 4 + j;
            float mu = musig[rowl * 2], rs = musig[rowl * 2 + 1];
            float* orow = out + (row0 + rowl) * (size_t)D_DIM;
            #pragma unroll
            for (int nt = 0; nt < 4; ++nt)
                orow[cols[nt]] = (Y[mt][nt][j] - mu) * rs * gm4[nt] + bt4[nt];
        }
}

extern "C" void kernel_launch(void* const* d_in, const int* in_sizes, int n_in,
                              void* d_out, int out_size, void* d_ws, size_t ws_size,
                              hipStream_t stream) {
    (void)in_sizes; (void)n_in; (void)out_size; (void)ws_size;
    const float* x     = (const float*)d_in[0];
    const float* Wq    = (const float*)d_in[1];
    const float* bq    = (const float*)d_in[2];
    const float* Wk    = (const float*)d_in[3];
    const float* bk    = (const float*)d_in[4];
    const float* Wv    = (const float*)d_in[5];
    const float* bv    = (const float*)d_in[6];
    const float* adj   = (const float*)d_in[7];
    const float* Wo    = (const float*)d_in[8];
    const float* bo    = (const float*)d_in[9];
    const float* gamma = (const float*)d_in[10];
    const float* beta  = (const float*)d_in[11];
    unsigned short* wt = (unsigned short*)d_ws;      // 4 * 512*512 bf16 = 2 MiB

    prep_weights<<<4096, 256, 0, stream>>>(Wq, Wk, Wv, Wo, wt);
    fused_attn<<<16384 / G_B, THREADS, SMEM_BYTES, stream>>>(
        x, wt, bq, bk, bv, adj, bo, gamma, beta, (float*)d_out);
}

// Round 7
// 1442.419 us; speedup vs baseline: 1.8313x; 1.4528x over previous
//
#include <hip/hip_runtime.h>
#include <hip/hip_bf16.h>

#define D_DIM 512
#define S_LEN 12
#define H_NUM 8
#define G_B 4
#define ROWS 48           // G_B * S_LEN = 3 exact M-tiles
#define THREADS 512       // 8 waves
#define WMAT 262144       // 512*512

// ---- kernel1 LDS (XOR-swizzled tiles) ----
#define X_OFF   0         // [48][512] bf16 = 49152
#define Q_OFF   49152     // [48][64] bf16 = 6144
#define K_OFF   55296
#define V_OFF   61440
#define P_OFF   67584     // 4 x [12][20] f32 = 3840
#define SMEM1   71424     // x2 = 142848 <= 163840 -> 2 blocks/CU

// ---- kernel2 LDS ----
#define AST_OFF 0         // [48][512] bf16 = 49152
#define RED_OFF 49152     // [48][17] f32 = 3264
#define MU_OFF  52416     // [48][2] f32 = 384
#define SMEM2   52800     // x2 = 105600 -> 2 blocks/CU

typedef __attribute__((ext_vector_type(8))) short bf16x8;
typedef __attribute__((ext_vector_type(4))) float f32x4;

__device__ __forceinline__ unsigned short f2bf(float f) {
    union { float f; unsigned u; } c; c.f = f;
    unsigned r = c.u + 0x7fffu + ((c.u >> 16) & 1u);
    return (unsigned short)(r >> 16);
}
__device__ __forceinline__ float bf2f(unsigned short u) {
    union { unsigned u; float f; } c; c.u = ((unsigned)u) << 16;
    return c.f;
}
// 16B-granule XOR swizzles (chunk ^= row&7)
__device__ __forceinline__ int xswc(int row, int col) {  // 512-col tiles
    return row * 512 + (((col >> 3) ^ (row & 7)) << 3) + (col & 7);
}
__device__ __forceinline__ int qsw(int row, int col) {   // 64-col tiles
    return row * 64 + (((col >> 3) ^ (row & 7)) << 3) + (col & 7);
}

__global__ void prep_weights(const float* __restrict__ Wq, const float* __restrict__ Wk,
                             const float* __restrict__ Wv, const float* __restrict__ Wo,
                             unsigned short* __restrict__ wt) {
    int idx = blockIdx.x * 256 + threadIdx.x;   // 0 .. 4*WMAT-1
    int mat = idx >> 18;
    int rem = idx & (WMAT - 1);
    int e = rem >> 9, d = rem & 511;
    const float* W = (mat == 0) ? Wq : (mat == 1) ? Wk : (mat == 2) ? Wv : Wo;
    wt[idx] = f2bf(W[d * D_DIM + e]);           // wt[mat][e][d] = W[d][e]
}

// ---------------- kernel 1: QKV + attention -> A (f32, into d_out) ----------------
__global__ __launch_bounds__(THREADS, 2) void qkv_attn(
    const float* __restrict__ x, const unsigned short* __restrict__ wt,
    const float* __restrict__ bq, const float* __restrict__ bk, const float* __restrict__ bv,
    const float* __restrict__ adj, float* __restrict__ aout)
{
    extern __shared__ char smem[];
    unsigned short* Xh = (unsigned short*)(smem + X_OFF);
    unsigned short* Qh = (unsigned short*)(smem + Q_OFF);
    unsigned short* Kh = (unsigned short*)(smem + K_OFF);
    unsigned short* Vh = (unsigned short*)(smem + V_OFF);
    float* Pl = (float*)(smem + P_OFF);         // [4][12][20]

    const int tid  = threadIdx.x;
    const int lane = tid & 63;
    const int w    = tid >> 6;          // wave 0..7
    const int lr   = lane & 15;
    const int lg   = lane >> 4;
    const int lr12 = (lr < 12) ? lr : 11;       // true clamp
    const size_t row0 = (size_t)blockIdx.x * ROWS;

    // stage X -> LDS bf16 (swizzled)
    #pragma unroll
    for (int it = 0; it < 12; ++it) {
        int idx = it * THREADS + tid;
        int r = idx >> 7, col = (idx & 127) << 2;
        float4 v = *(const float4*)(x + (row0 + r) * (size_t)D_DIM + col);
        ushort4 pk;
        pk.x = f2bf(v.x); pk.y = f2bf(v.y); pk.z = f2bf(v.z); pk.w = f2bf(v.w);
        *(ushort4*)(Xh + xswc(r, col)) = pk;
    }
    __syncthreads();

    // task split: waves 0-3 -> (Q, colt=w) + (V, colt=w); waves 4-7 -> (K, colt=w-4)
    const bool twoTask = (w < 4);
    const int colt = w & 3;
    const int colh = colt * 16 + lr;
    const int matA = twoTask ? 0 : 1;
    const int rb = w * S_LEN;

    #pragma unroll 1
    for (int h = 0; h < H_NUM; ++h) {
        f32x4 accA[3], accB[3];
        #pragma unroll
        for (int mt = 0; mt < 3; ++mt) {
            accA[mt] = (f32x4){0.f, 0.f, 0.f, 0.f};
            accB[mt] = (f32x4){0.f, 0.f, 0.f, 0.f};
        }
        const unsigned short* bAp = wt + (size_t)matA * WMAT + (h * 64 + colh) * D_DIM;
        const unsigned short* bBp = wt + (size_t)2 * WMAT + (h * 64 + colh) * D_DIM;
        #pragma unroll
        for (int ks = 0; ks < 16; ++ks) {
            bf16x8 af[3];
            #pragma unroll
            for (int mt = 0; mt < 3; ++mt)
                af[mt] = *(const bf16x8*)(Xh + xswc(mt * 16 + lr, ks * 32 + lg * 8));
            bf16x8 b0 = *(const bf16x8*)(bAp + ks * 32 + lg * 8);
            #pragma unroll
            for (int mt = 0; mt < 3; ++mt)
                accA[mt] = __builtin_amdgcn_mfma_f32_16x16x32_bf16(af[mt], b0, accA[mt], 0, 0, 0);
            if (twoTask) {
                bf16x8 b1 = *(const bf16x8*)(bBp + ks * 32 + lg * 8);
                #pragma unroll
                for (int mt = 0; mt < 3; ++mt)
                    accB[mt] = __builtin_amdgcn_mfma_f32_16x16x32_bf16(af[mt], b1, accB[mt], 0, 0, 0);
            }
        }
        {
            const float* bselA = twoTask ? bq : bk;
            unsigned short* TA = twoTask ? Qh : Kh;
            float biasA = bselA[h * 64 + colh];
            #pragma unroll
            for (int mt = 0; mt < 3; ++mt)
                #pragma unroll
                for (int j = 0; j < 4; ++j)
                    TA[qsw(mt * 16 + lg * 4 + j, colh)] = f2bf(accA[mt][j] + biasA);
            if (twoTask) {
                float biasB = bv[h * 64 + colh];
                #pragma unroll
                for (int mt = 0; mt < 3; ++mt)
                    #pragma unroll
                    for (int j = 0; j < 4; ++j)
                        Vh[qsw(mt * 16 + lg * 4 + j, colh)] = f2bf(accB[mt][j] + biasB);
            }
        }
        __syncthreads();   // Q/K/V complete

        if (twoTask) {     // attention for batch item w, head h
            f32x4 sacc = (f32x4){0.f, 0.f, 0.f, 0.f};
            #pragma unroll
            for (int k2 = 0; k2 < 2; ++k2) {
                bf16x8 ak = *(const bf16x8*)(Kh + qsw(rb + lr12, k2 * 32 + lg * 8));
                bf16x8 aq = *(const bf16x8*)(Qh + qsw(rb + lr12, k2 * 32 + lg * 8));
                sacc = __builtin_amdgcn_mfma_f32_16x16x32_bf16(ak, aq, sacc, 0, 0, 0);
            }
            float ab4[4] = {0.f, 0.f, 0.f, 0.f};
            if (lg < 3 && lr < 12) {
                float4 t4 = *(const float4*)(adj + (h * S_LEN + lr) * S_LEN + lg * 4);
                ab4[0] = t4.x; ab4[1] = t4.y; ab4[2] = t4.z; ab4[3] = t4.w;
            }
            float sc[4], e4[4];
            float m = -1e30f;
            #pragma unroll
            for (int j = 0; j < 4; ++j) {
                int t = lg * 4 + j;
                sc[j] = (t < 12) ? (sacc[j] * 0.125f + ab4[j]) : -1e30f;
                m = fmaxf(m, sc[j]);
            }
            m = fmaxf(m, __shfl_xor(m, 16));
            m = fmaxf(m, __shfl_xor(m, 32));
            float ssum = 0.f;
            #pragma unroll
            for (int j = 0; j < 4; ++j) { e4[j] = __expf(sc[j] - m); ssum += e4[j]; }
            ssum += __shfl_xor(ssum, 16);
            ssum += __shfl_xor(ssum, 32);
            float inv = 1.f / ssum;
            float* Pw = Pl + w * 240;
            if (lr < 12 && lg < 3) {
                f32x4 pvec = (f32x4){e4[0] * inv, e4[1] * inv, e4[2] * inv, e4[3] * inv};
                *(f32x4*)(Pw + lr * 20 + lg * 4) = pvec;
            }
            // same-wave P write -> read: no barrier needed (validated R5/R6)
            float vv[12];
            #pragma unroll
            for (int t = 0; t < 12; ++t) vv[t] = bf2f(Vh[qsw(rb + t, lane)]);
            #pragma unroll
            for (int ss = 0; ss < 12; ++ss) {
                f32x4 pa = *(const f32x4*)(Pw + ss * 20);
                f32x4 pb = *(const f32x4*)(Pw + ss * 20 + 4);
                f32x4 pc = *(const f32x4*)(Pw + ss * 20 + 8);
                float o = 0.f;
                #pragma unroll
                for (int t = 0; t < 4; ++t) o += pa[t] * vv[t];
                #pragma unroll
                for (int t = 0; t < 4; ++t) o += pb[t] * vv[4 + t];
                #pragma unroll
                for (int t = 0; t < 4; ++t) o += pc[t] * vv[8 + t];
                aout[(row0 + rb + ss) * (size_t)D_DIM + h * 64 + lane] = o;
            }
        }
        __syncthreads();   // A done; safe to overwrite Q/K/V next head
    }
}

// ---------------- kernel 2: out-proj + bias + residual + LayerNorm (in-place) ----------------
__global__ __launch_bounds__(THREADS, 2) void oproj_ln(
    const float* __restrict__ x, const unsigned short* __restrict__ wt,
    const float* __restrict__ bo, const float* __restrict__ gamma,
    const float* __restrict__ beta, float* __restrict__ out)
{
    extern __shared__ char smem[];
    unsigned short* Ast = (unsigned short*)(smem + AST_OFF);  // [48][512] bf16
    float* red   = (float*)(smem + RED_OFF);   // [48][17]
    float* musig = (float*)(smem + MU_OFF);    // [48][2]

    const int tid  = threadIdx.x;
    const int lane = tid & 63;
    const int w    = tid >> 6;
    const int lr   = lane & 15;
    const int lg   = lane >> 4;
    const size_t row0 = (size_t)blockIdx.x * ROWS;

    // stage A (f32 in out) -> LDS bf16 (swizzled); all reads precede the barrier,
    // all writes to these rows happen after it -> in-place safe, row-partitioned.
    #pragma unroll
    for (int it = 0; it < 12; ++it) {
        int idx = it * THREADS + tid;
        int r = idx >> 7, col = (idx & 127) << 2;
        float4 v = *(const float4*)(out + (row0 + r) * (size_t)D_DIM + col);
        ushort4 pk;
        pk.x = f2bf(v.x); pk.y = f2bf(v.y); pk.z = f2bf(v.z); pk.w = f2bf(v.w);
        *(ushort4*)(Ast + xswc(r, col)) = pk;
    }
    __syncthreads();

    f32x4 Y[3][4];
    #pragma unroll
    for (int mt = 0; mt < 3; ++mt)
        #pragma unroll
        for (int nt = 0; nt < 4; ++nt) Y[mt][nt] = (f32x4){0.f, 0.f, 0.f, 0.f};

    const unsigned short* obase = wt + (size_t)3 * WMAT + (w * 64 + lr) * D_DIM;
    #pragma unroll 2
    for (int ks = 0; ks < 16; ++ks) {
        bf16x8 afr[3];
        #pragma unroll
        for (int mt = 0; mt < 3; ++mt)
            afr[mt] = *(const bf16x8*)(Ast + xswc(mt * 16 + lr, ks * 32 + lg * 8));
        #pragma unroll
        for (int nt = 0; nt < 4; ++nt) {
            bf16x8 bfr = *(const bf16x8*)(obase + nt * 16 * D_DIM + ks * 32 + lg * 8);
            #pragma unroll
            for (int mt = 0; mt < 3; ++mt)
                Y[mt][nt] = __builtin_amdgcn_mfma_f32_16x16x32_bf16(afr[mt], bfr, Y[mt][nt], 0, 0, 0);
        }
    }

    // epilogue: +bo, +x (fp32), LayerNorm, store
    float bo4[4], gm4[4], bt4[4];
    int cols[4];
    #pragma unroll
    for (int nt = 0; nt < 4; ++nt) {
        cols[nt] = w * 64 + nt * 16 + lr;
        bo4[nt] = bo[cols[nt]]; gm4[nt] = gamma[cols[nt]]; bt4[nt] = beta[cols[nt]];
    }
    #pragma unroll
    for (int mt = 0; mt < 3; ++mt)
        #pragma unroll
        for (int j = 0; j < 4; ++j) {
            int rowl = mt * 16 + lg * 4 + j;
            const float* xrow = x + (row0 + rowl) * (size_t)D_DIM;
            float ps = 0.f, pq = 0.f;
            #pragma unroll
            for (int nt = 0; nt < 4; ++nt) {
                float y = Y[mt][nt][j] + bo4[nt] + xrow[cols[nt]];
                Y[mt][nt][j] = y;
                ps += y; pq += y * y;
            }
            ps += __shfl_xor(ps, 1); pq += __shfl_xor(pq, 1);
            ps += __shfl_xor(ps, 2); pq += __shfl_xor(pq, 2);
            ps += __shfl_xor(ps, 4); pq += __shfl_xor(pq, 4);
            ps += __shfl_xor(ps, 8); pq += __shfl_xor(pq, 8);
            if (lr == 0) { red[rowl * 17 + w * 2] = ps; red[rowl * 17 + w * 2 + 1] = pq; }
        }
    __syncthreads();
    if (tid < ROWS) {
        float s = 0.f, q = 0.f;
        #pragma unroll
        for (int w8 = 0; w8 < 8; ++w8) { s += red[tid * 17 + w8 * 2]; q += red[tid * 17 + w8 * 2 + 1]; }
        float mu = s * (1.f / 512.f);
        float var = q * (1.f / 512.f) - mu * mu;
        musig[tid * 2] = mu;
        musig[tid * 2 + 1] = rsqrtf(var + 1e-5f);
    }
    __syncthreads();
    #pragma unroll
    for (int mt = 0; mt < 3; ++mt)
        #pragma unroll
        for (int j = 0; j < 4; ++j) {
            int rowl = mt * 16 + lg * 4 + j;
            float mu = musig[rowl * 2], rs = musig[rowl * 2 + 1];
            float* orow = out + (row0 + rowl) * (size_t)D_DIM;
            #pragma unroll
            for (int nt = 0; nt < 4; ++nt)
                orow[cols[nt]] = (Y[mt][nt][j] - mu) * rs * gm4[nt] + bt4[nt];
        }
}

extern "C" void kernel_launch(void* const* d_in, const int* in_sizes, int n_in,
                              void* d_out, int out_size, void* d_ws, size_t ws_size,
                              hipStream_t stream) {
    (void)in_sizes; (void)n_in; (void)out_size; (void)ws_size;
    const float* x     = (const float*)d_in[0];
    const float* Wq    = (const float*)d_in[1];
    const float* bq    = (const float*)d_in[2];
    const float* Wk    = (const float*)d_in[3];
    const float* bk    = (const float*)d_in[4];
    const float* Wv    = (const float*)d_in[5];
    const float* bv    = (const float*)d_in[6];
    const float* adj   = (const float*)d_in[7];
    const float* Wo    = (const float*)d_in[8];
    const float* bo    = (const float*)d_in[9];
    const float* gamma = (const float*)d_in[10];
    const float* beta  = (const float*)d_in[11];
    unsigned short* wt = (unsigned short*)d_ws;      // 4 * 512*512 bf16 = 2 MiB
    float* outf = (float*)d_out;

    prep_weights<<<4096, 256, 0, stream>>>(Wq, Wk, Wv, Wo, wt);
    qkv_attn<<<16384 / G_B, THREADS, SMEM1, stream>>>(x, wt, bq, bk, bv, adj, outf);
    oproj_ln<<<16384 / G_B, THREADS, SMEM2, stream>>>(x, wt, bo, gamma, beta, outf);
}

// Round 8
// 1094.758 us; speedup vs baseline: 2.4128x; 1.3176x over previous
//
#include <hip/hip_runtime.h>
#include <hip/hip_bf16.h>

#define D_DIM 512
#define S_LEN 12
#define H_NUM 8
#define WMAT 262144       // 512*512

// ---- kernel1: G_B=8, 96 rows, 12 waves ----
#define G_B1 8
#define ROWS1 96          // 6 M-tiles
#define THREADS1 768      // 12 waves: wave = (mat, colt)
#define X_OFF   0         // [96][512] bf16 = 98304
#define Q_OFF   98304     // [96][64] bf16 = 12288
#define K_OFF   110592
#define V_OFF   122880
#define P_OFF   135168    // 8 x [12][20] f32 = 7680
#define SMEM1   142848    // 1 block/CU (12 waves)

// ---- kernel2 (unchanged from R7): G_B=4 ----
#define G_B2 4
#define ROWS2 48
#define THREADS2 512
#define AST_OFF 0         // [48][512] bf16 = 49152
#define RED_OFF 49152     // [48][17] f32 = 3264
#define MU_OFF  52416     // [48][2] f32 = 384
#define SMEM2   52800     // x2 -> 2 blocks/CU

typedef __attribute__((ext_vector_type(8))) short bf16x8;
typedef __attribute__((ext_vector_type(4))) float f32x4;

__device__ __forceinline__ unsigned short f2bf(float f) {
    union { float f; unsigned u; } c; c.f = f;
    unsigned r = c.u + 0x7fffu + ((c.u >> 16) & 1u);
    return (unsigned short)(r >> 16);
}
__device__ __forceinline__ float bf2f(unsigned short u) {
    union { unsigned u; float f; } c; c.u = ((unsigned)u) << 16;
    return c.f;
}
// 16B-granule XOR swizzles (chunk ^= row&7)
__device__ __forceinline__ int xswc(int row, int col) {  // 512-col tiles
    return row * 512 + (((col >> 3) ^ (row & 7)) << 3) + (col & 7);
}
__device__ __forceinline__ int qsw(int row, int col) {   // 64-col tiles
    return row * 64 + (((col >> 3) ^ (row & 7)) << 3) + (col & 7);
}

__global__ void prep_weights(const float* __restrict__ Wq, const float* __restrict__ Wk,
                             const float* __restrict__ Wv, const float* __restrict__ Wo,
                             unsigned short* __restrict__ wt) {
    int idx = blockIdx.x * 256 + threadIdx.x;   // 0 .. 4*WMAT-1
    int mat = idx >> 18;
    int rem = idx & (WMAT - 1);
    int e = rem >> 9, d = rem & 511;
    const float* W = (mat == 0) ? Wq : (mat == 1) ? Wk : (mat == 2) ? Wv : Wo;
    wt[idx] = f2bf(W[d * D_DIM + e]);           // wt[mat][e][d] = W[d][e]
}

// ---------------- kernel 1: QKV + attention -> A (f32, into d_out) ----------------
__global__ __launch_bounds__(THREADS1, 3) void qkv_attn(
    const float* __restrict__ x, const unsigned short* __restrict__ wt,
    const float* __restrict__ bq, const float* __restrict__ bk, const float* __restrict__ bv,
    const float* __restrict__ adj, float* __restrict__ aout)
{
    extern __shared__ char smem[];
    unsigned short* Xh = (unsigned short*)(smem + X_OFF);
    unsigned short* Qh = (unsigned short*)(smem + Q_OFF);
    unsigned short* Kh = (unsigned short*)(smem + K_OFF);
    unsigned short* Vh = (unsigned short*)(smem + V_OFF);
    float* Pl = (float*)(smem + P_OFF);         // [8][12][20]

    const int tid  = threadIdx.x;
    const int lane = tid & 63;
    const int w    = tid >> 6;          // wave 0..11
    const int lr   = lane & 15;
    const int lg   = lane >> 4;
    const int lr12 = (lr < 12) ? lr : 11;       // true clamp
    const size_t row0 = (size_t)blockIdx.x * ROWS1;

    // stage X -> LDS bf16 (swizzled): 12288 float4 chunks, 16 per thread
    #pragma unroll
    for (int it = 0; it < 16; ++it) {
        int idx = it * THREADS1 + tid;
        int r = idx >> 7, col = (idx & 127) << 2;
        float4 v = *(const float4*)(x + (row0 + r) * (size_t)D_DIM + col);
        ushort4 pk;
        pk.x = f2bf(v.x); pk.y = f2bf(v.y); pk.z = f2bf(v.z); pk.w = f2bf(v.w);
        *(ushort4*)(Xh + xswc(r, col)) = pk;
    }
    __syncthreads();

    // wave task: mat = w>>2 (0=Q,1=K,2=V), colt = w&3; owns all 6 M-tiles.
    const int mat  = w >> 2;
    const int colt = w & 3;
    const int colh = colt * 16 + lr;
    const float* bsel = (mat == 0) ? bq : (mat == 1) ? bk : bv;
    unsigned short* T = (mat == 0) ? Qh : (mat == 1) ? Kh : Vh;
    const int rb = w * S_LEN;                   // attention rows (waves 0-7)

    #pragma unroll 1
    for (int h = 0; h < H_NUM; ++h) {
        // ---------------- QKV projection for head h ----------------
        f32x4 acc[6];
        #pragma unroll
        for (int mt = 0; mt < 6; ++mt) acc[mt] = (f32x4){0.f, 0.f, 0.f, 0.f};

        const unsigned short* bAp = wt + (size_t)mat * WMAT + (h * 64 + colh) * D_DIM + lg * 8;
        bf16x8 bc = *(const bf16x8*)(bAp);      // B double-buffer: preload ks=0
        #pragma unroll
        for (int ks = 0; ks < 16; ++ks) {
            bf16x8 bn;
            if (ks < 15) bn = *(const bf16x8*)(bAp + (ks + 1) * 32);   // prefetch next
            #pragma unroll
            for (int mt = 0; mt < 6; ++mt) {
                bf16x8 af = *(const bf16x8*)(Xh + xswc(mt * 16 + lr, ks * 32 + lg * 8));
                acc[mt] = __builtin_amdgcn_mfma_f32_16x16x32_bf16(af, bc, acc[mt], 0, 0, 0);
            }
            if (ks < 15) bc = bn;
        }
        {
            float bias = bsel[h * 64 + colh];
            #pragma unroll
            for (int mt = 0; mt < 6; ++mt)
                #pragma unroll
                for (int j = 0; j < 4; ++j)
                    T[qsw(mt * 16 + lg * 4 + j, colh)] = f2bf(acc[mt][j] + bias);
        }
        __syncthreads();   // Q/K/V complete

        // ---------------- attention (waves 0-7 <-> batch items 0-7) ----------------
        if (w < 8) {
            f32x4 sacc = (f32x4){0.f, 0.f, 0.f, 0.f};
            #pragma unroll
            for (int k2 = 0; k2 < 2; ++k2) {
                bf16x8 ak = *(const bf16x8*)(Kh + qsw(rb + lr12, k2 * 32 + lg * 8));
                bf16x8 aq = *(const bf16x8*)(Qh + qsw(rb + lr12, k2 * 32 + lg * 8));
                sacc = __builtin_amdgcn_mfma_f32_16x16x32_bf16(ak, aq, sacc, 0, 0, 0);
            }
            float ab4[4] = {0.f, 0.f, 0.f, 0.f};
            if (lg < 3 && lr < 12) {
                float4 t4 = *(const float4*)(adj + (h * S_LEN + lr) * S_LEN + lg * 4);
                ab4[0] = t4.x; ab4[1] = t4.y; ab4[2] = t4.z; ab4[3] = t4.w;
            }
            float sc[4], e4[4];
            float m = -1e30f;
            #pragma unroll
            for (int j = 0; j < 4; ++j) {
                int t = lg * 4 + j;
                sc[j] = (t < 12) ? (sacc[j] * 0.125f + ab4[j]) : -1e30f;
                m = fmaxf(m, sc[j]);
            }
            m = fmaxf(m, __shfl_xor(m, 16));
            m = fmaxf(m, __shfl_xor(m, 32));
            float ssum = 0.f;
            #pragma unroll
            for (int j = 0; j < 4; ++j) { e4[j] = __expf(sc[j] - m); ssum += e4[j]; }
            ssum += __shfl_xor(ssum, 16);
            ssum += __shfl_xor(ssum, 32);
            float inv = 1.f / ssum;
            float* Pw = Pl + w * 240;
            if (lr < 12 && lg < 3) {
                f32x4 pvec = (f32x4){e4[0] * inv, e4[1] * inv, e4[2] * inv, e4[3] * inv};
                *(f32x4*)(Pw + lr * 20 + lg * 4) = pvec;
            }
            // same-wave P write -> read: no barrier needed (validated R5/R6/R7)
            float vv[12];
            #pragma unroll
            for (int t = 0; t < 12; ++t) vv[t] = bf2f(Vh[qsw(rb + t, lane)]);
            #pragma unroll
            for (int ss = 0; ss < 12; ++ss) {
                f32x4 pa = *(const f32x4*)(Pw + ss * 20);
                f32x4 pb = *(const f32x4*)(Pw + ss * 20 + 4);
                f32x4 pc = *(const f32x4*)(Pw + ss * 20 + 8);
                float o = 0.f;
                #pragma unroll
                for (int t = 0; t < 4; ++t) o += pa[t] * vv[t];
                #pragma unroll
                for (int t = 0; t < 4; ++t) o += pb[t] * vv[4 + t];
                #pragma unroll
                for (int t = 0; t < 4; ++t) o += pc[t] * vv[8 + t];
                aout[(row0 + rb + ss) * (size_t)D_DIM + h * 64 + lane] = o;
            }
        }
        __syncthreads();   // A consumers done; safe to overwrite Q/K/V next head
    }
}

// ---------------- kernel 2: out-proj + bias + residual + LayerNorm (in-place) ----------------
__global__ __launch_bounds__(THREADS2, 2) void oproj_ln(
    const float* __restrict__ x, const unsigned short* __restrict__ wt,
    const float* __restrict__ bo, const float* __restrict__ gamma,
    const float* __restrict__ beta, float* __restrict__ out)
{
    extern __shared__ char smem[];
    unsigned short* Ast = (unsigned short*)(smem + AST_OFF);  // [48][512] bf16
    float* red   = (float*)(smem + RED_OFF);   // [48][17]
    float* musig = (float*)(smem + MU_OFF);    // [48][2]

    const int tid  = threadIdx.x;
    const int lane = tid & 63;
    const int w    = tid >> 6;
    const int lr   = lane & 15;
    const int lg   = lane >> 4;
    const size_t row0 = (size_t)blockIdx.x * ROWS2;

    // stage A (f32 in out) -> LDS bf16 (swizzled); in-place safe (row-partitioned)
    #pragma unroll
    for (int it = 0; it < 12; ++it) {
        int idx = it * THREADS2 + tid;
        int r = idx >> 7, col = (idx & 127) << 2;
        float4 v = *(const float4*)(out + (row0 + r) * (size_t)D_DIM + col);
        ushort4 pk;
        pk.x = f2bf(v.x); pk.y = f2bf(v.y); pk.z = f2bf(v.z); pk.w = f2bf(v.w);
        *(ushort4*)(Ast + xswc(r, col)) = pk;
    }
    __syncthreads();

    f32x4 Y[3][4];
    #pragma unroll
    for (int mt = 0; mt < 3; ++mt)
        #pragma unroll
        for (int nt = 0; nt < 4; ++nt) Y[mt][nt] = (f32x4){0.f, 0.f, 0.f, 0.f};

    const unsigned short* obase = wt + (size_t)3 * WMAT + (w * 64 + lr) * D_DIM;
    #pragma unroll 2
    for (int ks = 0; ks < 16; ++ks) {
        bf16x8 afr[3];
        #pragma unroll
        for (int mt = 0; mt < 3; ++mt)
            afr[mt] = *(const bf16x8*)(Ast + xswc(mt * 16 + lr, ks * 32 + lg * 8));
        #pragma unroll
        for (int nt = 0; nt < 4; ++nt) {
            bf16x8 bfr = *(const bf16x8*)(obase + nt * 16 * D_DIM + ks * 32 + lg * 8);
            #pragma unroll
            for (int mt = 0; mt < 3; ++mt)
                Y[mt][nt] = __builtin_amdgcn_mfma_f32_16x16x32_bf16(afr[mt], bfr, Y[mt][nt], 0, 0, 0);
        }
    }

    // epilogue: +bo, +x (fp32), LayerNorm, store
    float bo4[4], gm4[4], bt4[4];
    int cols[4];
    #pragma unroll
    for (int nt = 0; nt < 4; ++nt) {
        cols[nt] = w * 64 + nt * 16 + lr;
        bo4[nt] = bo[cols[nt]]; gm4[nt] = gamma[cols[nt]]; bt4[nt] = beta[cols[nt]];
    }
    #pragma unroll
    for (int mt = 0; mt < 3; ++mt)
        #pragma unroll
        for (int j = 0; j < 4; ++j) {
            int rowl = mt * 16 + lg * 4 + j;
            const float* xrow = x + (row0 + rowl) * (size_t)D_DIM;
            float ps = 0.f, pq = 0.f;
            #pragma unroll
            for (int nt = 0; nt < 4; ++nt) {
                float y = Y[mt][nt][j] + bo4[nt] + xrow[cols[nt]];
                Y[mt][nt][j] = y;
                ps += y; pq += y * y;
            }
            ps += __shfl_xor(ps, 1); pq += __shfl_xor(pq, 1);
            ps += __shfl_xor(ps, 2); pq += __shfl_xor(pq, 2);
            ps += __shfl_xor(ps, 4); pq += __shfl_xor(pq, 4);
            ps += __shfl_xor(ps, 8); pq += __shfl_xor(pq, 8);
            if (lr == 0) { red[rowl * 17 + w * 2] = ps; red[rowl * 17 + w * 2 + 1] = pq; }
        }
    __syncthreads();
    if (tid < ROWS2) {
        float s = 0.f, q = 0.f;
        #pragma unroll
        for (int w8 = 0; w8 < 8; ++w8) { s += red[tid * 17 + w8 * 2]; q += red[tid * 17 + w8 * 2 + 1]; }
        float mu = s * (1.f / 512.f);
        float var = q * (1.f / 512.f) - mu * mu;
        musig[tid * 2] = mu;
        musig[tid * 2 + 1] = rsqrtf(var + 1e-5f);
    }
    __syncthreads();
    #pragma unroll
    for (int mt = 0; mt < 3; ++mt)
        #pragma unroll
        for (int j = 0; j < 4; ++j) {
            int rowl = mt * 16 + lg * 4 + j;
            float mu = musig[rowl * 2], rs = musig[rowl * 2 + 1];
            float* orow = out + (row0 + rowl) * (size_t)D_DIM;
            #pragma unroll
            for (int nt = 0; nt < 4; ++nt)
                orow[cols[nt]] = (Y[mt][nt][j] - mu) * rs * gm4[nt] + bt4[nt];
        }
}

extern "C" void kernel_launch(void* const* d_in, const int* in_sizes, int n_in,
                              void* d_out, int out_size, void* d_ws, size_t ws_size,
                              hipStream_t stream) {
    (void)in_sizes; (void)n_in; (void)out_size; (void)ws_size;
    const float* x     = (const float*)d_in[0];
    const float* Wq    = (const float*)d_in[1];
    const float* bq    = (const float*)d_in[2];
    const float* Wk    = (const float*)d_in[3];
    const float* bk    = (const float*)d_in[4];
    const float* Wv    = (const float*)d_in[5];
    const float* bv    = (const float*)d_in[6];
    const float* adj   = (const float*)d_in[7];
    const float* Wo    = (const float*)d_in[8];
    const float* bo    = (const float*)d_in[9];
    const float* gamma = (const float*)d_in[10];
    const float* beta  = (const float*)d_in[11];
    unsigned short* wt = (unsigned short*)d_ws;      // 4 * 512*512 bf16 = 2 MiB
    float* outf = (float*)d_out;

    prep_weights<<<4096, 256, 0, stream>>>(Wq, Wk, Wv, Wo, wt);
    qkv_attn<<<16384 / G_B1, THREADS1, SMEM1, stream>>>(x, wt, bq, bk, bv, adj, outf);
    oproj_ln<<<16384 / G_B2, THREADS2, SMEM2, stream>>>(x, wt, bo, gamma, beta, outf);
}